// Round 3
// baseline (321.365 us; speedup 1.0000x reference)
//
#include <hip/hip_runtime.h>
#include <math.h>
#include <float.h>

#define DDIM 1024   // D
#define PDIM 32     // pattern_dim
#define NPAT 256    // n_patterns
#define TOPK 4
#define BLOCK 256
#define GTOK 8      // tokens per matrix sweep (8 -> low VGPR, high occupancy)
#define XSS (DDIM + DDIM / 32)   // 1056: +1 float pad per 32 floats
#define GEMM_GRID 1024

// ---------------------------------------------------------------------------
// K0: routing — per token: h = x@W^T, sim = h@K^T, top-4 (tie->lower idx),
// softmax weights. Writes tki/tkw and bumps per-pattern counts.
// (verbatim-verified from R1/R2)
__global__ __launch_bounds__(BLOCK) void route_kernel(
    const float* __restrict__ x,
    const float* __restrict__ hasher_w,   // [PDIM, DDIM]
    const float* __restrict__ keys,       // [NPAT, PDIM]
    int*   __restrict__ tki,              // [ntok, TOPK]
    float* __restrict__ tkw,              // [ntok, TOPK]
    int*   __restrict__ cnt)              // [NPAT]
{
    __shared__ float4 x4_s[DDIM / 4];
    __shared__ float4 h4_s[PDIM / 4];
    __shared__ float  wk_s[TOPK];
    __shared__ int    idx_s[TOPK];
    __shared__ float  wred_v[4];
    __shared__ int    wred_i[4];

    float* x_s = (float*)x4_s;
    float* h_s = (float*)h4_s;

    const int t   = blockIdx.x;
    const int tid = threadIdx.x;

    x4_s[tid] = ((const float4*)(x + (size_t)t * DDIM))[tid];
    __syncthreads();

    {   // h[p], 8 lanes per p
        const int p   = tid >> 3;
        const int seg = tid & 7;
        const float4* wrow = (const float4*)(hasher_w + p * DDIM + seg * 128);
        const float4* xs   = (const float4*)(x_s + seg * 128);
        float acc = 0.f;
        #pragma unroll
        for (int i = 0; i < 32; ++i) {
            float4 w4 = wrow[i];
            float4 a4 = xs[i];
            acc = fmaf(w4.x, a4.x, acc);
            acc = fmaf(w4.y, a4.y, acc);
            acc = fmaf(w4.z, a4.z, acc);
            acc = fmaf(w4.w, a4.w, acc);
        }
        acc += __shfl_down(acc, 4, 8);
        acc += __shfl_down(acc, 2, 8);
        acc += __shfl_down(acc, 1, 8);
        if (seg == 0) h_s[p] = acc;
    }
    __syncthreads();

    float myv;
    {   // sim[n], one thread per pattern
        const float4* krow = (const float4*)(keys + tid * PDIM);
        float acc = 0.f;
        #pragma unroll
        for (int i = 0; i < 8; ++i) {
            float4 k4 = krow[i];
            float4 hh = h4_s[i];
            acc = fmaf(k4.x, hh.x, acc);
            acc = fmaf(k4.y, hh.y, acc);
            acc = fmaf(k4.z, hh.z, acc);
            acc = fmaf(k4.w, hh.w, acc);
        }
        myv = acc;
    }

    for (int r = 0; r < TOPK; ++r) {
        float v = myv;
        int   i = tid;
        #pragma unroll
        for (int off = 32; off > 0; off >>= 1) {
            float ov = __shfl_xor(v, off, 64);
            int   oi = __shfl_xor(i, off, 64);
            if (ov > v || (ov == v && oi < i)) { v = ov; i = oi; }
        }
        const int w = tid >> 6;
        if ((tid & 63) == 0) { wred_v[w] = v; wred_i[w] = i; }
        __syncthreads();
        if (tid == 0) {
            float bv = wred_v[0]; int bi = wred_i[0];
            #pragma unroll
            for (int j = 1; j < 4; ++j) {
                if (wred_v[j] > bv || (wred_v[j] == bv && wred_i[j] < bi)) {
                    bv = wred_v[j]; bi = wred_i[j];
                }
            }
            idx_s[r] = bi;
            wk_s[r]  = bv;
        }
        __syncthreads();
        if (tid == idx_s[r]) myv = -FLT_MAX;
    }

    if (tid == 0) {
        float m = wk_s[0];
        #pragma unroll
        for (int j = 1; j < TOPK; ++j) m = fmaxf(m, wk_s[j]);
        float s = 0.f, e[TOPK];
        #pragma unroll
        for (int j = 0; j < TOPK; ++j) { e[j] = expf(wk_s[j] - m); s += e[j]; }
        #pragma unroll
        for (int j = 0; j < TOPK; ++j) {
            const float wj = e[j] / s;
            tki[t * TOPK + j] = idx_s[j];
            tkw[t * TOPK + j] = wj;
            atomicAdd(&cnt[idx_s[j]], 1);
        }
    }
}

// ---------------------------------------------------------------------------
// K1: single-block scan + CSR fill + balanced group list.
//  offs[257]  : entry-slot CSR offsets per pattern
//  glist[]    : one descriptor per (pattern, group of <=GTOK tokens): p<<16|j
//  ngroups[1] : total group count
//  etok/ew/slotof : per-entry token index / weight*scale / slot of (t,k)
__global__ __launch_bounds__(NPAT) void scanfill_kernel(
    const int* __restrict__ cnt,
    const int* __restrict__ tki, const float* __restrict__ tkw,
    const float* __restrict__ scale_p,
    int* __restrict__ offs, int* __restrict__ glist, int* __restrict__ ngroups,
    int* __restrict__ etok, float* __restrict__ ew, int* __restrict__ slotof,
    int nent)
{
    __shared__ int s[NPAT];
    __shared__ int g2[NPAT];
    __shared__ int cur[NPAT];
    const int tid = threadIdx.x;

    const int v = cnt[tid];
    s[tid] = v;
    __syncthreads();
    for (int off = 1; off < NPAT; off <<= 1) {
        int t = 0;
        if (tid >= off) t = s[tid - off];
        __syncthreads();
        s[tid] += t;
        __syncthreads();
    }
    const int incl = s[tid];
    const int excl = incl - v;
    offs[tid + 1] = incl;
    if (tid == 0) offs[0] = 0;
    cur[tid] = excl;

    const int ngp = (v + GTOK - 1) / GTOK;
    g2[tid] = ngp;
    __syncthreads();
    for (int off = 1; off < NPAT; off <<= 1) {
        int t = 0;
        if (tid >= off) t = g2[tid - off];
        __syncthreads();
        g2[tid] += t;
        __syncthreads();
    }
    const int gbase = g2[tid] - ngp;
    if (tid == NPAT - 1) ngroups[0] = g2[NPAT - 1];
    for (int j = 0; j < ngp; ++j) glist[gbase + j] = (tid << 16) | j;
    __syncthreads();

    const float sc = scale_p[0];
    for (int e = tid; e < nent; e += NPAT) {
        const int p = tki[e];
        const int slot = atomicAdd(&cur[p], 1);
        etok[slot] = e >> 2;
        ew[slot]   = tkw[e] * sc;
        slotof[e]  = slot;
    }
}

// ---------------------------------------------------------------------------
// K2: pattern-major grouped GEMM over a flat, balanced group list.
// Each group = (pattern p, <=GTOK tokens). Grid-stride loop over groups.
// MODE 0: store weighted contribution rows to contrib[slot].
// MODE 1: atomicAdd into out (pre-initialized to x).
template <int MODE>
__global__ __launch_bounds__(BLOCK, 4) void pattern_gemm_kernel(
    const float* __restrict__ x,
    const float* __restrict__ vd,          // [NPAT, DDIM, PDIM]
    const float* __restrict__ vu,          // [NPAT, PDIM, DDIM]
    const int* __restrict__ offs,
    const int* __restrict__ glist,
    const int* __restrict__ ngroups_p,
    const int* __restrict__ etok,
    const float* __restrict__ ew,
    float* __restrict__ dst,               // contrib (MODE 0) or out (MODE 1)
    int nent)
{
    __shared__ float xs[GTOK * XSS];       // 33.8 KB padded x rows
    __shared__ float red[4][8][36];        // wave partials (stride 36: no conflicts)
    __shared__ float projT[PDIM][GTOK];    // silu(x@vd) * w, transposed
    __shared__ int   gt[GTOK];
    __shared__ float gw[GTOK];
    __shared__ int   gs[GTOK];

    const int tid = threadIdx.x;
    const int ng  = ngroups_p[0];

    for (int gi = blockIdx.x; gi < ng; gi += gridDim.x) {
        const int desc  = glist[gi];
        const int p     = desc >> 16;
        const int j     = desc & 0xffff;
        const int start = offs[p] + j * GTOK;
        const int gv    = min(GTOK, offs[p + 1] - start);

        if (tid < GTOK) {
            int tok, slot; float w;
            if (tid < gv) {
                tok = etok[start + tid]; w = ew[start + tid]; slot = start + tid;
            } else {
                tok = etok[start]; w = 0.f; slot = nent;     // dummy row
            }
            gt[tid] = tok; gw[tid] = w; gs[tid] = slot;
        }
        __syncthreads();

        const float* vdp = vd + (size_t)p * DDIM * PDIM;
        const float* vup = vu + (size_t)p * PDIM * DDIM;

        // stage GTOK x rows into padded LDS
        #pragma unroll
        for (int g = 0; g < GTOK; ++g) {
            const float4 xv = ((const float4*)(x + (size_t)gt[g] * DDIM))[tid];
            const int d = tid * 4;
            *(float4*)&xs[g * XSS + d + (d >> 5)] = xv;
        }
        __syncthreads();

        // ---- phase A: proj[g][pp] = x[g] . vd[:,pp]
        const int pp4 = tid & 7;     // pp quad: pp4*4..pp4*4+3
        const int seg = tid >> 3;    // d range seg*32..seg*32+31
        float4 acc[GTOK];
        #pragma unroll
        for (int g = 0; g < GTOK; ++g) acc[g] = make_float4(0.f, 0.f, 0.f, 0.f);

        #pragma unroll
        for (int i4 = 0; i4 < 8; ++i4) {
            const int d0 = seg * 32 + i4 * 4;
            const float* b2 = vdp + (size_t)d0 * PDIM + pp4 * 4;
            const float4 v0 = *(const float4*)(b2);
            const float4 v1 = *(const float4*)(b2 + PDIM);
            const float4 v2 = *(const float4*)(b2 + 2 * PDIM);
            const float4 v3 = *(const float4*)(b2 + 3 * PDIM);
            const int xoff = d0 + seg;    // d0 + (d0>>5)
            #pragma unroll
            for (int g = 0; g < GTOK; ++g) {
                const float4 xg = *(const float4*)&xs[g * XSS + xoff];
                acc[g].x = fmaf(xg.x, v0.x, acc[g].x);
                acc[g].y = fmaf(xg.x, v0.y, acc[g].y);
                acc[g].z = fmaf(xg.x, v0.z, acc[g].z);
                acc[g].w = fmaf(xg.x, v0.w, acc[g].w);
                acc[g].x = fmaf(xg.y, v1.x, acc[g].x);
                acc[g].y = fmaf(xg.y, v1.y, acc[g].y);
                acc[g].z = fmaf(xg.y, v1.z, acc[g].z);
                acc[g].w = fmaf(xg.y, v1.w, acc[g].w);
                acc[g].x = fmaf(xg.z, v2.x, acc[g].x);
                acc[g].y = fmaf(xg.z, v2.y, acc[g].y);
                acc[g].z = fmaf(xg.z, v2.z, acc[g].z);
                acc[g].w = fmaf(xg.z, v2.w, acc[g].w);
                acc[g].x = fmaf(xg.w, v3.x, acc[g].x);
                acc[g].y = fmaf(xg.w, v3.y, acc[g].y);
                acc[g].z = fmaf(xg.w, v3.z, acc[g].z);
                acc[g].w = fmaf(xg.w, v3.w, acc[g].w);
            }
        }

        // reduce across the 8 segs within each wave (lane bits 3..5)
        #pragma unroll
        for (int g = 0; g < GTOK; ++g) {
            #pragma unroll
            for (int off = 8; off <= 32; off <<= 1) {
                acc[g].x += __shfl_xor(acc[g].x, off, 64);
                acc[g].y += __shfl_xor(acc[g].y, off, 64);
                acc[g].z += __shfl_xor(acc[g].z, off, 64);
                acc[g].w += __shfl_xor(acc[g].w, off, 64);
            }
        }
        const int wv = tid >> 6;
        if ((tid & 0x38) == 0) {          // one lane per (wave, pp4)
            #pragma unroll
            for (int g = 0; g < GTOK; ++g)
                *(float4*)&red[wv][pp4][g * 4] = acc[g];
        }
        __syncthreads();

        // final reduce over 4 waves + silu + weight -> projT[pp][g]
        {
            const int pp = tid >> 3, g = tid & 7;       // 32*8 = 256 = BLOCK
            const int q = pp >> 2, cmp = g * 4 + (pp & 3);
            const float s = red[0][q][cmp] + red[1][q][cmp]
                          + red[2][q][cmp] + red[3][q][cmp];
            const float pj = s / (1.f + expf(-s));      // silu
            projT[pp][g] = pj * gw[g];
        }
        __syncthreads();

        // ---- phase B: o[g][d] = proj[g] . vu[:,d]
        float4 o[GTOK];
        #pragma unroll
        for (int g = 0; g < GTOK; ++g) o[g] = make_float4(0.f, 0.f, 0.f, 0.f);

        #pragma unroll
        for (int pp = 0; pp < PDIM; ++pp) {
            const float4 vu4 = ((const float4*)(vup + (size_t)pp * DDIM))[tid];
            const float4 pa = *(const float4*)&projT[pp][0];
            const float4 pb = *(const float4*)&projT[pp][4];
            o[0].x = fmaf(pa.x, vu4.x, o[0].x); o[0].y = fmaf(pa.x, vu4.y, o[0].y);
            o[0].z = fmaf(pa.x, vu4.z, o[0].z); o[0].w = fmaf(pa.x, vu4.w, o[0].w);
            o[1].x = fmaf(pa.y, vu4.x, o[1].x); o[1].y = fmaf(pa.y, vu4.y, o[1].y);
            o[1].z = fmaf(pa.y, vu4.z, o[1].z); o[1].w = fmaf(pa.y, vu4.w, o[1].w);
            o[2].x = fmaf(pa.z, vu4.x, o[2].x); o[2].y = fmaf(pa.z, vu4.y, o[2].y);
            o[2].z = fmaf(pa.z, vu4.z, o[2].z); o[2].w = fmaf(pa.z, vu4.w, o[2].w);
            o[3].x = fmaf(pa.w, vu4.x, o[3].x); o[3].y = fmaf(pa.w, vu4.y, o[3].y);
            o[3].z = fmaf(pa.w, vu4.z, o[3].z); o[3].w = fmaf(pa.w, vu4.w, o[3].w);
            o[4].x = fmaf(pb.x, vu4.x, o[4].x); o[4].y = fmaf(pb.x, vu4.y, o[4].y);
            o[4].z = fmaf(pb.x, vu4.z, o[4].z); o[4].w = fmaf(pb.x, vu4.w, o[4].w);
            o[5].x = fmaf(pb.y, vu4.x, o[5].x); o[5].y = fmaf(pb.y, vu4.y, o[5].y);
            o[5].z = fmaf(pb.y, vu4.z, o[5].z); o[5].w = fmaf(pb.y, vu4.w, o[5].w);
            o[6].x = fmaf(pb.z, vu4.x, o[6].x); o[6].y = fmaf(pb.z, vu4.y, o[6].y);
            o[6].z = fmaf(pb.z, vu4.z, o[6].z); o[6].w = fmaf(pb.z, vu4.w, o[6].w);
            o[7].x = fmaf(pb.w, vu4.x, o[7].x); o[7].y = fmaf(pb.w, vu4.y, o[7].y);
            o[7].z = fmaf(pb.w, vu4.z, o[7].z); o[7].w = fmaf(pb.w, vu4.w, o[7].w);
        }

        if (MODE == 0) {
            #pragma unroll
            for (int g = 0; g < GTOK; ++g)
                ((float4*)(dst + (size_t)gs[g] * DDIM))[tid] = o[g];
        } else {
            #pragma unroll
            for (int g = 0; g < GTOK; ++g) {
                if (g < gv) {
                    float* op = dst + (size_t)gt[g] * DDIM + tid * 4;
                    atomicAdd(op + 0, o[g].x);
                    atomicAdd(op + 1, o[g].y);
                    atomicAdd(op + 2, o[g].z);
                    atomicAdd(op + 3, o[g].w);
                }
            }
        }
        __syncthreads();   // LDS reused next group
    }
}

// ---------------------------------------------------------------------------
// K3: out[t] = x[t] + sum_k contrib[slot_of[t][k]]  (weights already applied)
__global__ __launch_bounds__(BLOCK) void combine_kernel(
    const float* __restrict__ x, const float* __restrict__ contrib,
    const int* __restrict__ slotof, float* __restrict__ out)
{
    __shared__ int sl[TOPK];
    const int t = blockIdx.x, tid = threadIdx.x;
    if (tid < TOPK) sl[tid] = slotof[t * TOPK + tid];
    __syncthreads();
    float4 r = ((const float4*)(x + (size_t)t * DDIM))[tid];
    #pragma unroll
    for (int k = 0; k < TOPK; ++k) {
        const float4 cv = ((const float4*)(contrib + (size_t)sl[k] * DDIM))[tid];
        r.x += cv.x; r.y += cv.y; r.z += cv.z; r.w += cv.w;
    }
    ((float4*)(out + (size_t)t * DDIM))[tid] = r;
}

// ---------------------------------------------------------------------------
extern "C" void kernel_launch(void* const* d_in, const int* in_sizes, int n_in,
                              void* d_out, int out_size, void* d_ws, size_t ws_size,
                              hipStream_t stream) {
    const float* x        = (const float*)d_in[0];
    const float* hasher_w = (const float*)d_in[1];
    const float* keys     = (const float*)d_in[2];
    const float* vd       = (const float*)d_in[3];
    const float* vu       = (const float*)d_in[4];
    const float* scale    = (const float*)d_in[5];
    float* out = (float*)d_out;

    const int ntok = in_sizes[0] / DDIM;        // B*T
    const int nent = ntok * TOPK;
    const int maxgroups = nent / GTOK + NPAT;   // fragmentation bound

    // workspace layout
    char* w = (char*)d_ws;
    const size_t o_cnt  = 0;                                      // 256 int
    const size_t o_offs = 1024;                                   // 257 int
    const size_t o_ngrp = 2560;                                   // 1 int
    const size_t o_gls  = 2816;                                   // maxgroups int
    const size_t o_tki  = o_gls  + ((size_t)maxgroups * 4 + 255 & ~(size_t)255);
    const size_t o_tkw  = o_tki  + (size_t)nent * 4;
    const size_t o_etok = o_tkw  + (size_t)nent * 4;
    const size_t o_ew   = o_etok + (size_t)nent * 4;
    const size_t o_slot = o_ew   + (size_t)nent * 4;
    const size_t o_ctb  = (o_slot + (size_t)nent * 4 + 255) & ~(size_t)255;
    const size_t needA  = o_ctb + (size_t)(nent + 1) * DDIM * 4;  // +1 dummy row
    const size_t needB  = o_ctb;

    int*   cnt    = (int*)(w + o_cnt);
    int*   offs   = (int*)(w + o_offs);
    int*   ngrp   = (int*)(w + o_ngrp);
    int*   glist  = (int*)(w + o_gls);
    int*   tki    = (int*)(w + o_tki);
    float* tkw    = (float*)(w + o_tkw);
    int*   etok   = (int*)(w + o_etok);
    float* ew     = (float*)(w + o_ew);
    int*   slotof = (int*)(w + o_slot);
    float* contrib= (float*)(w + o_ctb);

    hipMemsetAsync(cnt, 0, NPAT * sizeof(int), stream);
    hipLaunchKernelGGL(route_kernel, dim3(ntok), dim3(BLOCK), 0, stream,
                       x, hasher_w, keys, tki, tkw, cnt);
    hipLaunchKernelGGL(scanfill_kernel, dim3(1), dim3(NPAT), 0, stream,
                       cnt, tki, tkw, scale, offs, glist, ngrp,
                       etok, ew, slotof, nent);

    if (ws_size >= needA) {
        hipLaunchKernelGGL((pattern_gemm_kernel<0>), dim3(GEMM_GRID), dim3(BLOCK),
                           0, stream, x, vd, vu, offs, glist, ngrp, etok, ew,
                           contrib, nent);
        hipLaunchKernelGGL(combine_kernel, dim3(ntok), dim3(BLOCK), 0, stream,
                           x, contrib, slotof, out);
    } else if (ws_size >= needB) {
        hipMemcpyAsync(out, x, (size_t)ntok * DDIM * 4, hipMemcpyDeviceToDevice,
                       stream);
        hipLaunchKernelGGL((pattern_gemm_kernel<1>), dim3(GEMM_GRID), dim3(BLOCK),
                           0, stream, x, vd, vu, offs, glist, ngrp, etok, ew,
                           out, nent);
    }
}

// Round 4
// 248.265 us; speedup vs baseline: 1.2944x; 1.2944x over previous
//
#include <hip/hip_runtime.h>
#include <math.h>
#include <float.h>

#define DDIM 1024   // D
#define PDIM 32     // pattern_dim
#define NPAT 256    // n_patterns
#define TOPK 4
#define BLOCK 256
#define GT   16     // tokens per tile
#define DCH  256    // d-chunk per block
#define NCH  4      // d-chunks (DDIM/DCH)

// ---------------------------------------------------------------------------
// K0: routing — per token: h = x@W^T, sim = h@K^T, top-4 (tie->lower idx),
// softmax weights. (verbatim-verified R1/R2/R3)
__global__ __launch_bounds__(BLOCK) void route_kernel(
    const float* __restrict__ x,
    const float* __restrict__ hasher_w,   // [PDIM, DDIM]
    const float* __restrict__ keys,       // [NPAT, PDIM]
    int*   __restrict__ tki,              // [ntok, TOPK]
    float* __restrict__ tkw,              // [ntok, TOPK]
    int*   __restrict__ cnt)              // [NPAT]
{
    __shared__ float4 x4_s[DDIM / 4];
    __shared__ float4 h4_s[PDIM / 4];
    __shared__ float  wk_s[TOPK];
    __shared__ int    idx_s[TOPK];
    __shared__ float  wred_v[4];
    __shared__ int    wred_i[4];

    float* x_s = (float*)x4_s;
    float* h_s = (float*)h4_s;

    const int t   = blockIdx.x;
    const int tid = threadIdx.x;

    x4_s[tid] = ((const float4*)(x + (size_t)t * DDIM))[tid];
    __syncthreads();

    {   // h[p], 8 lanes per p
        const int p   = tid >> 3;
        const int seg = tid & 7;
        const float4* wrow = (const float4*)(hasher_w + p * DDIM + seg * 128);
        const float4* xs   = (const float4*)(x_s + seg * 128);
        float acc = 0.f;
        #pragma unroll
        for (int i = 0; i < 32; ++i) {
            float4 w4 = wrow[i];
            float4 a4 = xs[i];
            acc = fmaf(w4.x, a4.x, acc);
            acc = fmaf(w4.y, a4.y, acc);
            acc = fmaf(w4.z, a4.z, acc);
            acc = fmaf(w4.w, a4.w, acc);
        }
        acc += __shfl_down(acc, 4, 8);
        acc += __shfl_down(acc, 2, 8);
        acc += __shfl_down(acc, 1, 8);
        if (seg == 0) h_s[p] = acc;
    }
    __syncthreads();

    float myv;
    {   // sim[n], one thread per pattern
        const float4* krow = (const float4*)(keys + tid * PDIM);
        float acc = 0.f;
        #pragma unroll
        for (int i = 0; i < 8; ++i) {
            float4 k4 = krow[i];
            float4 hh = h4_s[i];
            acc = fmaf(k4.x, hh.x, acc);
            acc = fmaf(k4.y, hh.y, acc);
            acc = fmaf(k4.z, hh.z, acc);
            acc = fmaf(k4.w, hh.w, acc);
        }
        myv = acc;
    }

    for (int r = 0; r < TOPK; ++r) {
        float v = myv;
        int   i = tid;
        #pragma unroll
        for (int off = 32; off > 0; off >>= 1) {
            float ov = __shfl_xor(v, off, 64);
            int   oi = __shfl_xor(i, off, 64);
            if (ov > v || (ov == v && oi < i)) { v = ov; i = oi; }
        }
        const int w = tid >> 6;
        if ((tid & 63) == 0) { wred_v[w] = v; wred_i[w] = i; }
        __syncthreads();
        if (tid == 0) {
            float bv = wred_v[0]; int bi = wred_i[0];
            #pragma unroll
            for (int j = 1; j < 4; ++j) {
                if (wred_v[j] > bv || (wred_v[j] == bv && wred_i[j] < bi)) {
                    bv = wred_v[j]; bi = wred_i[j];
                }
            }
            idx_s[r] = bi;
            wk_s[r]  = bv;
        }
        __syncthreads();
        if (tid == idx_s[r]) myv = -FLT_MAX;
    }

    if (tid == 0) {
        float m = wk_s[0];
        #pragma unroll
        for (int j = 1; j < TOPK; ++j) m = fmaxf(m, wk_s[j]);
        float s = 0.f, e[TOPK];
        #pragma unroll
        for (int j = 0; j < TOPK; ++j) { e[j] = expf(wk_s[j] - m); s += e[j]; }
        #pragma unroll
        for (int j = 0; j < TOPK; ++j) {
            const float wj = e[j] / s;
            tki[t * TOPK + j] = idx_s[j];
            tkw[t * TOPK + j] = wj;
            atomicAdd(&cnt[idx_s[j]], 1);
        }
    }
}

// ---------------------------------------------------------------------------
// K1: single-block scan + CSR fill (glist removed; grid is fixed now)
__global__ __launch_bounds__(NPAT) void scanfill_kernel(
    const int* __restrict__ cnt,
    const int* __restrict__ tki, const float* __restrict__ tkw,
    const float* __restrict__ scale_p,
    int* __restrict__ offs,
    int* __restrict__ etok, float* __restrict__ ew, int* __restrict__ slotof,
    int nent)
{
    __shared__ int s[NPAT];
    __shared__ int cur[NPAT];
    const int tid = threadIdx.x;

    const int v = cnt[tid];
    s[tid] = v;
    __syncthreads();
    for (int off = 1; off < NPAT; off <<= 1) {
        int t = 0;
        if (tid >= off) t = s[tid - off];
        __syncthreads();
        s[tid] += t;
        __syncthreads();
    }
    const int incl = s[tid];
    offs[tid + 1] = incl;
    if (tid == 0) offs[0] = 0;
    cur[tid] = incl - v;
    __syncthreads();

    const float sc = scale_p[0];
    for (int e = tid; e < nent; e += NPAT) {
        const int p = tki[e];
        const int slot = atomicAdd(&cur[p], 1);
        etok[slot] = e >> 2;
        ew[slot]   = tkw[e] * sc;
        slotof[e]  = slot;
    }
}

// ---------------------------------------------------------------------------
// K2: down-projection, d-split. Block (p, c): stages vd[p][c*256:+256][:] in
// LDS (read from HBM exactly once), loops over p's tokens in tiles of 16,
// writes PARTIAL proj sums to part[c][slot][pp]. No silu here (sum first).
__global__ __launch_bounds__(BLOCK, 2) void proj_kernel(
    const float* __restrict__ x,
    const float* __restrict__ vd,          // [NPAT, DDIM, PDIM]
    const int* __restrict__ offs,
    const int* __restrict__ etok,
    float* __restrict__ part,              // [NCH][nent+1][PDIM]
    int nent)
{
    __shared__ float vd_s[DCH * PDIM];     // 32 KB
    __shared__ float x_s[GT * DCH];        // 16 KB
    __shared__ float red[4][8][68];        // 8.7 KB, 68-pad: conflict-free
    __shared__ int   gt[GT];
    __shared__ int   gs[GT];

    const int p   = blockIdx.x >> 2;
    const int c   = blockIdx.x & 3;
    const int tid = threadIdx.x;
    const int off0 = offs[p];
    const int n    = offs[p + 1] - off0;
    if (n == 0) return;

    // stage vd chunk (coalesced, 8 float4 per thread)
    const float* vdp = vd + (size_t)p * DDIM * PDIM + (size_t)c * DCH * PDIM;
    #pragma unroll
    for (int k = 0; k < 8; ++k)
        ((float4*)vd_s)[k * 256 + tid] = ((const float4*)vdp)[k * 256 + tid];
    __syncthreads();

    const int pp4 = tid & 7;      // pp quad
    const int seg = tid >> 3;     // 0..31, 8 d's each
    float* partc = part + (size_t)c * (size_t)(nent + 1) * PDIM;

    for (int t0 = 0; t0 < n; t0 += GT) {
        const int gv = min(GT, n - t0);
        if (tid < GT) {
            if (tid < gv) { gt[tid] = etok[off0 + t0 + tid]; gs[tid] = off0 + t0 + tid; }
            else          { gt[tid] = etok[off0];            gs[tid] = nent; }
        }
        __syncthreads();

        // stage x tile chunk (16 rows x 256 floats, coalesced)
        #pragma unroll
        for (int k = 0; k < 4; ++k) {
            const int q  = k * 256 + tid;      // float4 index
            const int g  = q >> 6, fi = q & 63;
            ((float4*)x_s)[g * 64 + fi] =
                *(const float4*)(x + (size_t)gt[g] * DDIM + c * DCH + fi * 4);
        }
        __syncthreads();

        float4 acc[GT];
        #pragma unroll
        for (int g = 0; g < GT; ++g) acc[g] = make_float4(0.f, 0.f, 0.f, 0.f);

        #pragma unroll
        for (int i4 = 0; i4 < 2; ++i4) {
            const int d0 = seg * 8 + i4 * 4;
            const float4 v0 = *(const float4*)&vd_s[(d0 + 0) * PDIM + pp4 * 4];
            const float4 v1 = *(const float4*)&vd_s[(d0 + 1) * PDIM + pp4 * 4];
            const float4 v2 = *(const float4*)&vd_s[(d0 + 2) * PDIM + pp4 * 4];
            const float4 v3 = *(const float4*)&vd_s[(d0 + 3) * PDIM + pp4 * 4];
            #pragma unroll
            for (int g = 0; g < GT; ++g) {
                const float4 xg = *(const float4*)&x_s[g * DCH + d0];
                acc[g].x = fmaf(xg.x, v0.x, acc[g].x);
                acc[g].y = fmaf(xg.x, v0.y, acc[g].y);
                acc[g].z = fmaf(xg.x, v0.z, acc[g].z);
                acc[g].w = fmaf(xg.x, v0.w, acc[g].w);
                acc[g].x = fmaf(xg.y, v1.x, acc[g].x);
                acc[g].y = fmaf(xg.y, v1.y, acc[g].y);
                acc[g].z = fmaf(xg.y, v1.z, acc[g].z);
                acc[g].w = fmaf(xg.y, v1.w, acc[g].w);
                acc[g].x = fmaf(xg.z, v2.x, acc[g].x);
                acc[g].y = fmaf(xg.z, v2.y, acc[g].y);
                acc[g].z = fmaf(xg.z, v2.z, acc[g].z);
                acc[g].w = fmaf(xg.z, v2.w, acc[g].w);
                acc[g].x = fmaf(xg.w, v3.x, acc[g].x);
                acc[g].y = fmaf(xg.w, v3.y, acc[g].y);
                acc[g].z = fmaf(xg.w, v3.z, acc[g].z);
                acc[g].w = fmaf(xg.w, v3.w, acc[g].w);
            }
        }

        // in-wave reduce over 8 segs (lane bits 3..5)
        #pragma unroll
        for (int g = 0; g < GT; ++g) {
            #pragma unroll
            for (int off = 8; off <= 32; off <<= 1) {
                acc[g].x += __shfl_xor(acc[g].x, off, 64);
                acc[g].y += __shfl_xor(acc[g].y, off, 64);
                acc[g].z += __shfl_xor(acc[g].z, off, 64);
                acc[g].w += __shfl_xor(acc[g].w, off, 64);
            }
        }
        const int wv = tid >> 6;
        if ((tid & 0x38) == 0) {
            #pragma unroll
            for (int g = 0; g < GT; ++g)
                *(float4*)&red[wv][pp4][g * 4] = acc[g];
        }
        __syncthreads();

        // cross-wave reduce + write partial proj (coalesced 128B rows)
        #pragma unroll
        for (int r = 0; r < 2; ++r) {
            const int idx = tid + r * BLOCK;       // 0..511
            const int g = idx >> 5, pp = idx & 31;
            const int q = pp >> 2, cmp = g * 4 + (pp & 3);
            const float s = red[0][q][cmp] + red[1][q][cmp]
                          + red[2][q][cmp] + red[3][q][cmp];
            partc[(size_t)gs[g] * PDIM + pp] = s;
        }
        __syncthreads();   // protect gt/gs/red/x_s before next tile
    }
}

// ---------------------------------------------------------------------------
// K3: up-projection, d-split. Block (p, c): stages vu[p][:][c*256:+256] in
// LDS (HBM once), loops over tiles: proj = silu(sum of 4 partials)*w, then
// o[g][d'] = proj . vu. MODE 0: store contrib[slot][chunk]. MODE 1: atomicAdd
// into out (pre-initialized to x).
template <int MODE>
__global__ __launch_bounds__(BLOCK, 4) void up_kernel(
    const float* __restrict__ vu,          // [NPAT, PDIM, DDIM]
    const int* __restrict__ offs,
    const int* __restrict__ etok,
    const float* __restrict__ ew,
    const float* __restrict__ part,        // [NCH][nent+1][PDIM]
    float* __restrict__ dst,               // contrib (MODE 0) or out (MODE 1)
    int nent)
{
    __shared__ float vu_s[PDIM * DCH];     // 32 KB
    __shared__ float projT[PDIM][20];      // [pp][g], pad 20
    __shared__ int   gt[GT];
    __shared__ float gw[GT];
    __shared__ int   gs[GT];

    const int p   = blockIdx.x >> 2;
    const int c   = blockIdx.x & 3;
    const int tid = threadIdx.x;
    const int off0 = offs[p];
    const int n    = offs[p + 1] - off0;
    if (n == 0) return;

    const size_t PS = (size_t)(nent + 1) * PDIM;   // part slice stride

    // stage vu chunk: 32 rows x 256 floats (coalesced)
    const float* vup = vu + (size_t)p * PDIM * DDIM + (size_t)c * DCH;
    #pragma unroll
    for (int k = 0; k < 8; ++k) {
        const int q  = k * 256 + tid;      // float4 index, 2048 total
        const int pp = q >> 6, fi = q & 63;
        *(float4*)&vu_s[pp * DCH + fi * 4] =
            *(const float4*)(vup + (size_t)pp * DDIM + fi * 4);
    }
    __syncthreads();

    const int gq   = tid >> 6;    // wave -> 4 tokens
    const int lane = tid & 63;    // -> 4 d's

    for (int t0 = 0; t0 < n; t0 += GT) {
        const int gv = min(GT, n - t0);
        if (tid < GT) {
            if (tid < gv) {
                gt[tid] = etok[off0 + t0 + tid];
                gw[tid] = ew[off0 + t0 + tid];
                gs[tid] = off0 + t0 + tid;
            } else {
                gt[tid] = etok[off0]; gw[tid] = 0.f; gs[tid] = nent;
            }
        }
        __syncthreads();

        // proj = silu(sum of 4 d-chunk partials) * weight
        #pragma unroll
        for (int r = 0; r < 2; ++r) {
            const int idx = tid + r * BLOCK;
            const int g = idx >> 5, pp = idx & 31;
            const size_t row = (size_t)gs[g] * PDIM + pp;
            const float s = part[row] + part[PS + row]
                          + part[2 * PS + row] + part[3 * PS + row];
            const float pj = s / (1.f + expf(-s));
            projT[pp][g] = pj * gw[g];
        }
        __syncthreads();

        float4 o0 = make_float4(0.f, 0.f, 0.f, 0.f);
        float4 o1 = o0, o2 = o0, o3 = o0;
        #pragma unroll
        for (int pp = 0; pp < PDIM; ++pp) {
            const float4 pj4 = *(const float4*)&projT[pp][gq * 4];
            const float4 vu4 = *(const float4*)&vu_s[pp * DCH + lane * 4];
            o0.x = fmaf(pj4.x, vu4.x, o0.x); o0.y = fmaf(pj4.x, vu4.y, o0.y);
            o0.z = fmaf(pj4.x, vu4.z, o0.z); o0.w = fmaf(pj4.x, vu4.w, o0.w);
            o1.x = fmaf(pj4.y, vu4.x, o1.x); o1.y = fmaf(pj4.y, vu4.y, o1.y);
            o1.z = fmaf(pj4.y, vu4.z, o1.z); o1.w = fmaf(pj4.y, vu4.w, o1.w);
            o2.x = fmaf(pj4.z, vu4.x, o2.x); o2.y = fmaf(pj4.z, vu4.y, o2.y);
            o2.z = fmaf(pj4.z, vu4.z, o2.z); o2.w = fmaf(pj4.z, vu4.w, o2.w);
            o3.x = fmaf(pj4.w, vu4.x, o3.x); o3.y = fmaf(pj4.w, vu4.y, o3.y);
            o3.z = fmaf(pj4.w, vu4.z, o3.z); o3.w = fmaf(pj4.w, vu4.w, o3.w);
        }

        if (MODE == 0) {
            float4 ov[4] = {o0, o1, o2, o3};
            #pragma unroll
            for (int j = 0; j < 4; ++j)
                *(float4*)(dst + (size_t)gs[gq * 4 + j] * DDIM + c * DCH + lane * 4) = ov[j];
        } else {
            float4 ov[4] = {o0, o1, o2, o3};
            #pragma unroll
            for (int j = 0; j < 4; ++j) {
                if (gq * 4 + j < gv) {
                    float* op = dst + (size_t)gt[gq * 4 + j] * DDIM + c * DCH + lane * 4;
                    atomicAdd(op + 0, ov[j].x);
                    atomicAdd(op + 1, ov[j].y);
                    atomicAdd(op + 2, ov[j].z);
                    atomicAdd(op + 3, ov[j].w);
                }
            }
        }
        __syncthreads();   // protect projT/gs before next tile
    }
}

// ---------------------------------------------------------------------------
// K4: out[t] = x[t] + sum_k contrib[slotof[t][k]]  (verbatim-verified)
__global__ __launch_bounds__(BLOCK) void combine_kernel(
    const float* __restrict__ x, const float* __restrict__ contrib,
    const int* __restrict__ slotof, float* __restrict__ out)
{
    __shared__ int sl[TOPK];
    const int t = blockIdx.x, tid = threadIdx.x;
    if (tid < TOPK) sl[tid] = slotof[t * TOPK + tid];
    __syncthreads();
    float4 r = ((const float4*)(x + (size_t)t * DDIM))[tid];
    #pragma unroll
    for (int k = 0; k < TOPK; ++k) {
        const float4 cv = ((const float4*)(contrib + (size_t)sl[k] * DDIM))[tid];
        r.x += cv.x; r.y += cv.y; r.z += cv.z; r.w += cv.w;
    }
    ((float4*)(out + (size_t)t * DDIM))[tid] = r;
}

// ---------------------------------------------------------------------------
extern "C" void kernel_launch(void* const* d_in, const int* in_sizes, int n_in,
                              void* d_out, int out_size, void* d_ws, size_t ws_size,
                              hipStream_t stream) {
    const float* x        = (const float*)d_in[0];
    const float* hasher_w = (const float*)d_in[1];
    const float* keys     = (const float*)d_in[2];
    const float* vd       = (const float*)d_in[3];
    const float* vu       = (const float*)d_in[4];
    const float* scale    = (const float*)d_in[5];
    float* out = (float*)d_out;

    const int ntok = in_sizes[0] / DDIM;        // B*T
    const int nent = ntok * TOPK;

    // workspace layout
    char* w = (char*)d_ws;
    const size_t o_cnt  = 0;                                      // 256 int
    const size_t o_offs = 1024;                                   // 257 int
    const size_t o_tki  = 2560;                                   // nent int
    const size_t o_tkw  = o_tki  + (size_t)nent * 4;
    const size_t o_etok = o_tkw  + (size_t)nent * 4;
    const size_t o_ew   = o_etok + (size_t)nent * 4;
    const size_t o_slot = o_ew   + (size_t)nent * 4;
    const size_t o_part = (o_slot + (size_t)nent * 4 + 255) & ~(size_t)255;
    const size_t partsz = (size_t)NCH * (size_t)(nent + 1) * PDIM * 4;
    const size_t o_ctb  = (o_part + partsz + 255) & ~(size_t)255;
    const size_t needPart    = o_ctb;                              // atomic path
    const size_t needContrib = o_ctb + (size_t)(nent + 1) * DDIM * 4;

    int*   cnt    = (int*)(w + o_cnt);
    int*   offs   = (int*)(w + o_offs);
    int*   tki    = (int*)(w + o_tki);
    float* tkw    = (float*)(w + o_tkw);
    int*   etok   = (int*)(w + o_etok);
    float* ew     = (float*)(w + o_ew);
    int*   slotof = (int*)(w + o_slot);
    float* part   = (float*)(w + o_part);
    float* contrib= (float*)(w + o_ctb);

    hipMemsetAsync(cnt, 0, NPAT * sizeof(int), stream);
    hipLaunchKernelGGL(route_kernel, dim3(ntok), dim3(BLOCK), 0, stream,
                       x, hasher_w, keys, tki, tkw, cnt);
    hipLaunchKernelGGL(scanfill_kernel, dim3(1), dim3(NPAT), 0, stream,
                       cnt, tki, tkw, scale, offs, etok, ew, slotof, nent);
    hipLaunchKernelGGL(proj_kernel, dim3(NPAT * NCH), dim3(BLOCK), 0, stream,
                       x, vd, offs, etok, part, nent);

    if (ws_size >= needContrib) {
        hipLaunchKernelGGL((up_kernel<0>), dim3(NPAT * NCH), dim3(BLOCK), 0, stream,
                           vu, offs, etok, ew, part, contrib, nent);
        hipLaunchKernelGGL(combine_kernel, dim3(ntok), dim3(BLOCK), 0, stream,
                           x, contrib, slotof, out);
    } else if (ws_size >= needPart) {
        hipMemcpyAsync(out, x, (size_t)ntok * DDIM * 4, hipMemcpyDeviceToDevice,
                       stream);
        hipLaunchKernelGGL((up_kernel<1>), dim3(NPAT * NCH), dim3(BLOCK), 0, stream,
                           vu, offs, etok, ew, part, out, nent);
    }
}